// Round 2
// baseline (1050.926 us; speedup 1.0000x reference)
//
#include <hip/hip_runtime.h>
#include <hip/hip_bf16.h>

typedef __attribute__((ext_vector_type(8))) short bf16x8;
typedef __attribute__((ext_vector_type(4))) float f32x4;

__device__ __forceinline__ float bfu(unsigned short u){
  union{ unsigned int i; float f; } c; c.i = ((unsigned)u) << 16; return c.f;
}
__device__ __forceinline__ float ldval(const void* p, int i, int f32){
  return f32 ? ((const float*)p)[i] : bfu(((const unsigned short*)p)[i]);
}
__device__ __forceinline__ bf16x8 packbf8(float4 u, float4 v){
  union { bf16x8 v8; __hip_bfloat16 h[8]; } r;
  r.h[0]=__float2bfloat16(u.x); r.h[1]=__float2bfloat16(u.y);
  r.h[2]=__float2bfloat16(u.z); r.h[3]=__float2bfloat16(u.w);
  r.h[4]=__float2bfloat16(v.x); r.h[5]=__float2bfloat16(v.y);
  r.h[6]=__float2bfloat16(v.z); r.h[7]=__float2bfloat16(v.w);
  return r.v8;
}
__device__ __forceinline__ float lrelu(float v){ return v > 0.f ? v : 0.2f*v; }

// ---- dtype detect: fp32 data read as bf16 has wild exponents; true bf16 N(0,1) maxes ~6
__global__ void detect(const unsigned short* __restrict__ xh, int* __restrict__ flag){
  int i = blockIdx.x*256 + threadIdx.x;       // 4096 samples, always in-bounds
  float v = fabsf(bfu(xh[i]));
  if (v > 1e4f) atomicOr(flag, 1);
}

// ---- canonicalize weights: Bt1=W1^T bf16, W2t=W2^T bf16, resWc=resW^T bf16, smalls fp32
__global__ void prep(const void* W1, const void* resW, const void* W2,
                     const void* a1s, const void* a1d, const void* b1,
                     const void* g, const void* bt,
                     const void* a2s, const void* a2d, const void* b2,
                     __hip_bfloat16* __restrict__ Bt1, __hip_bfloat16* __restrict__ W2t,
                     __hip_bfloat16* __restrict__ resWc,
                     float* att1s, float* att1d, float* bias1f, float* gf, float* bfta,
                     float* att2s, float* att2d, float* bias2f, const int* flag){
  int f = *flag;
  int idx = blockIdx.x*256 + threadIdx.x;
  if (idx < 16384){ int c=idx>>7, k=idx&127; Bt1[idx]  = __float2bfloat16(ldval(W1,  k*128+c, f)); }
  else if (idx < 24576){ int i=idx-16384, c=i>>7, k=i&127; W2t[i]  = __float2bfloat16(ldval(W2,  k*64+c,  f)); }
  else if (idx < 40960){ int i=idx-24576, c=i>>7, k=i&127; resWc[i]= __float2bfloat16(ldval(resW,k*128+c, f)); }
  else if (idx < 41088) att1s [idx-40960] = ldval(a1s, idx-40960, f);
  else if (idx < 41216) att1d [idx-41088] = ldval(a1d, idx-41088, f);
  else if (idx < 41344) bias1f[idx-41216] = ldval(b1,  idx-41216, f);
  else if (idx < 41472) gf    [idx-41344] = ldval(g,   idx-41344, f);
  else if (idx < 41600) bfta  [idx-41472] = ldval(bt,  idx-41472, f);
  else if (idx < 41664) att2s [idx-41600] = ldval(a2s, idx-41600, f);
  else if (idx < 41728) att2d [idx-41664] = ldval(a2d, idx-41664, f);
  else if (idx < 41792) bias2f[idx-41728] = ldval(b2,  idx-41728, f);
}

// ---- GEMM1: h1b[N,128] = bf16(x @ W1)   (MFMA 16x16x32)
__global__ __launch_bounds__(256) void gemm1(const void* __restrict__ xp,
                  const __hip_bfloat16* __restrict__ Bt1,
                  __hip_bfloat16* __restrict__ h1b, const int* __restrict__ flag, int nn){
  int f32 = *flag;
  int wave = threadIdx.x >> 6, lane = threadIdx.x & 63;
  int m = lane & 15, q = lane >> 4;
  int n0 = blockIdx.x * 16;
  int row = n0 + m; if (row >= nn) row = nn - 1;
  f32x4 acc[2];
  acc[0] = (f32x4){0.f,0.f,0.f,0.f}; acc[1] = (f32x4){0.f,0.f,0.f,0.f};
  #pragma unroll
  for (int kk=0; kk<4; ++kk){
    bf16x8 a;
    if (!f32) a = *(const bf16x8*)((const __hip_bfloat16*)xp + (size_t)row*128 + kk*32 + q*8);
    else { const float4* fp = (const float4*)((const float*)xp + (size_t)row*128 + kk*32 + q*8);
           a = packbf8(fp[0], fp[1]); }
    #pragma unroll
    for (int ct=0; ct<2; ++ct){
      int c = wave*32 + ct*16 + m;
      bf16x8 b = *(const bf16x8*)(Bt1 + (size_t)c*128 + kk*32 + q*8);
      acc[ct] = __builtin_amdgcn_mfma_f32_16x16x32_bf16(a, b, acc[ct], 0, 0, 0);
    }
  }
  #pragma unroll
  for (int ct=0; ct<2; ++ct){
    int c = wave*32 + ct*16 + m;
    #pragma unroll
    for (int i=0;i<4;++i){
      int r = n0 + q*4 + i;
      if (r < nn) h1b[(size_t)r*128 + c] = __float2bfloat16(acc[ct][i]);
    }
  }
}

// ---- GEMM2: h2[N,64] = fp32( h @ W2 ), h read from d_out per flag dtype
__global__ __launch_bounds__(256) void gemm2(const void* __restrict__ hp,
                  const __hip_bfloat16* __restrict__ W2t,
                  float* __restrict__ h2, const int* __restrict__ flag, int nn){
  int f32 = *flag;
  int wave = threadIdx.x >> 6, lane = threadIdx.x & 63;
  int m = lane & 15, q = lane >> 4;
  int n0 = blockIdx.x * 16;
  int row = n0 + m; if (row >= nn) row = nn - 1;
  f32x4 acc = (f32x4){0.f,0.f,0.f,0.f};
  #pragma unroll
  for (int kk=0; kk<4; ++kk){
    bf16x8 a;
    if (!f32) a = *(const bf16x8*)((const __hip_bfloat16*)hp + (size_t)row*128 + kk*32 + q*8);
    else { const float4* fp = (const float4*)((const float*)hp + (size_t)row*128 + kk*32 + q*8);
           a = packbf8(fp[0], fp[1]); }
    int c = wave*16 + m;
    bf16x8 b = *(const bf16x8*)(W2t + (size_t)c*128 + kk*32 + q*8);
    acc = __builtin_amdgcn_mfma_f32_16x16x32_bf16(a, b, acc, 0, 0, 0);
  }
  int c = wave*16 + m;
  #pragma unroll
  for (int i=0;i<4;++i){
    int r = n0 + q*4 + i;
    if (r < nn) h2[(size_t)r*64 + c] = acc[i];
  }
}

// ---- attention dots
__global__ void attdot1(const __hip_bfloat16* __restrict__ h1b,
                        const float* __restrict__ att1s, const float* __restrict__ att1d,
                        float* __restrict__ as1, float* __restrict__ ad1, int nn){
  int gid = blockIdx.x*256 + threadIdx.x;
  if (gid >= nn*8) return;
  int node = gid >> 3, h = gid & 7;
  const bf16x8* hp = (const bf16x8*)(h1b + (size_t)node*128 + h*16);
  bf16x8 v0 = hp[0], v1 = hp[1];
  float s=0.f, d=0.f;
  #pragma unroll
  for (int j=0;j<8;++j){
    float a = bfu((unsigned short)v0[j]);
    s += a*att1s[h*16+j]; d += a*att1d[h*16+j];
  }
  #pragma unroll
  for (int j=0;j<8;++j){
    float a = bfu((unsigned short)v1[j]);
    s += a*att1s[h*16+8+j]; d += a*att1d[h*16+8+j];
  }
  as1[gid]=s; ad1[gid]=d;
}

__global__ void attdot2(const float* __restrict__ h2,
                        const float* __restrict__ att2s, const float* __restrict__ att2d,
                        float* __restrict__ as2, float* __restrict__ ad2, int nn){
  int gid = blockIdx.x*256 + threadIdx.x;
  if (gid >= nn) return;
  const float4* hp = (const float4*)(h2 + (size_t)gid*64);
  float s=0.f, d=0.f;
  #pragma unroll
  for (int t=0;t<16;++t){
    float4 v = hp[t];
    s += v.x*att2s[t*4] + v.y*att2s[t*4+1] + v.z*att2s[t*4+2] + v.w*att2s[t*4+3];
    d += v.x*att2d[t*4] + v.y*att2d[t*4+1] + v.z*att2d[t*4+2] + v.w*att2d[t*4+3];
  }
  as2[gid]=s; ad2[gid]=d;
}

// ---- CSR build
__global__ void count_edges(const int* __restrict__ ei, int* __restrict__ cnt, int E, int nn){
  int e = blockIdx.x*256 + threadIdx.x;
  if (e < E){ int d = ei[E+e]; if ((unsigned)d < (unsigned)nn) atomicAdd(&cnt[d], 1); }
}

__global__ void scan_part(const int* __restrict__ cnt, int* __restrict__ part, int n){
  __shared__ int red[256];
  int t = threadIdx.x;
  int base = blockIdx.x*1024 + t*4;
  int s = 0;
  #pragma unroll
  for (int j=0;j<4;++j){ int i = base + j; if (i < n) s += cnt[i]; }
  red[t] = s; __syncthreads();
  for (int off=128; off>0; off>>=1){
    if (t < off) red[t] += red[t+off];
    __syncthreads();
  }
  if (t == 0) part[blockIdx.x] = red[0];
}

__global__ void scan_mid(int* __restrict__ part, int nb, int* __restrict__ row_ptr, int n){
  __shared__ int sd[256];
  int t = threadIdx.x;
  int v = (t < nb) ? part[t] : 0;
  sd[t] = v; __syncthreads();
  for (int off=1; off<256; off<<=1){
    int xv = (t >= off) ? sd[t-off] : 0;
    __syncthreads();
    sd[t] += xv;
    __syncthreads();
  }
  if (t < nb) part[t] = sd[t] - v;
  if (t == 0) row_ptr[n] = sd[255];
}

__global__ void scan_write(const int* __restrict__ cnt, const int* __restrict__ part,
                           int* __restrict__ row_ptr, int n){
  __shared__ int sd[256];
  int t = threadIdx.x;
  int base = blockIdx.x*1024 + t*4;
  int v0=0,v1=0,v2=0,v3=0;
  if (base   < n) v0 = cnt[base];
  if (base+1 < n) v1 = cnt[base+1];
  if (base+2 < n) v2 = cnt[base+2];
  if (base+3 < n) v3 = cnt[base+3];
  int s = v0+v1+v2+v3;
  sd[t] = s; __syncthreads();
  for (int off=1; off<256; off<<=1){
    int xv = (t >= off) ? sd[t-off] : 0;
    __syncthreads();
    sd[t] += xv;
    __syncthreads();
  }
  int run = part[blockIdx.x] + sd[t] - s;
  if (base   < n) row_ptr[base]   = run; run += v0;
  if (base+1 < n) row_ptr[base+1] = run; run += v1;
  if (base+2 < n) row_ptr[base+2] = run; run += v2;
  if (base+3 < n) row_ptr[base+3] = run;
}

__global__ void fill_csr(const int* __restrict__ ei, const int* __restrict__ row_ptr,
                         int* __restrict__ cur, int* __restrict__ csr, int E, int nn){
  int e = blockIdx.x*256 + threadIdx.x;
  if (e < E){
    int d = ei[E+e];
    if ((unsigned)d < (unsigned)nn){
      int pos = row_ptr[d] + atomicAdd(&cur[d], 1);
      if ((unsigned)pos < (unsigned)E) csr[pos] = ei[e];
    }
  }
}

// ---- layer-1 aggregate + residual(recomputed) + LayerNorm + ELU, 1 wave/node
__global__ __launch_bounds__(256) void agg1(
    const __hip_bfloat16* __restrict__ h1b,
    const float* __restrict__ as1, const float* __restrict__ ad1,
    const int* __restrict__ rowp, const int* __restrict__ csr,
    const void* __restrict__ xp, const __hip_bfloat16* __restrict__ resWc,
    const float* __restrict__ bias1f, const float* __restrict__ gf,
    const float* __restrict__ bfta,
    const int* __restrict__ flag, void* __restrict__ dout, int nn, int Etot){
  __shared__ float xs[4][128];
  int f32 = *flag;
  int w = threadIdx.x >> 6, lane = threadIdx.x & 63;
  int n = blockIdx.x*4 + w;
  if (n >= nn) return;
  // stage this node's x row (for residual recompute)
  if (!f32){
    ushort2 u = ((const ushort2*)((const unsigned short*)xp + (size_t)n*128))[lane];
    xs[w][lane*2] = bfu(u.x); xs[w][lane*2+1] = bfu(u.y);
  } else {
    float2 u = ((const float2*)((const float*)xp + (size_t)n*128))[lane];
    xs[w][lane*2] = u.x; xs[w][lane*2+1] = u.y;
  }
  int h = lane >> 3, c0 = lane*2;
  // residual: r = (x @ resW)[n, c0..c0+1]
  float r0 = 0.f, r1 = 0.f;
  const bf16x8* ca = (const bf16x8*)(resWc + (size_t)c0*128);
  const bf16x8* cb = (const bf16x8*)(resWc + (size_t)(c0+1)*128);
  #pragma unroll 2
  for (int kk=0; kk<16; ++kk){
    bf16x8 a = ca[kk], b = cb[kk];
    #pragma unroll
    for (int j=0;j<8;++j){
      float xv = xs[w][kk*8+j];
      r0 += xv * bfu((unsigned short)a[j]);
      r1 += xv * bfu((unsigned short)b[j]);
    }
  }
  // softmax-weighted gather (self-loop + incoming edges); no max-shift (|e|<=~10), clamp 30
  float adst = ad1[n*8 + h];
  float e0 = fminf(lrelu(as1[n*8 + h] + adst), 30.f);
  float wgt = __expf(e0);
  __hip_bfloat162 hv = *(const __hip_bfloat162*)(h1b + (size_t)n*128 + c0);
  float acc0 = wgt*__bfloat162float(hv.x), acc1 = wgt*__bfloat162float(hv.y), den = wgt;
  int p = rowp[n], pe = rowp[n+1];
  if (p < 0) p = 0; if (pe > Etot) pe = Etot;
  for (; p < pe; ++p){
    int s = csr[p];
    if ((unsigned)s >= (unsigned)nn) continue;
    float ev = fminf(lrelu(as1[s*8 + h] + adst), 30.f);
    float wv = __expf(ev);
    __hip_bfloat162 xv2 = *(const __hip_bfloat162*)(h1b + (size_t)s*128 + c0);
    acc0 += wv*__bfloat162float(xv2.x); acc1 += wv*__bfloat162float(xv2.y); den += wv;
  }
  float inv = 1.f/(den + 1e-16f);
  float o0 = acc0*inv + r0 + bias1f[c0];
  float o1 = acc1*inv + r1 + bias1f[c0+1];
  // LayerNorm over 128 (2 ch/lane, 64-lane butterfly)
  float s1 = o0 + o1, s2 = o0*o0 + o1*o1;
  #pragma unroll
  for (int off=32; off>0; off>>=1){
    s1 += __shfl_xor(s1, off);
    s2 += __shfl_xor(s2, off);
  }
  float mu  = s1 * (1.f/128.f);
  float var = s2 * (1.f/128.f) - mu*mu;
  float rstd = rsqrtf(var + 1e-5f);
  o0 = (o0 - mu)*rstd*gf[c0]   + bfta[c0];
  o1 = (o1 - mu)*rstd*gf[c0+1] + bfta[c0+1];
  o0 = o0 > 0.f ? o0 : __expf(o0) - 1.f;
  o1 = o1 > 0.f ? o1 : __expf(o1) - 1.f;
  if (!f32){
    __hip_bfloat162 o2; o2.x = __float2bfloat16(o0); o2.y = __float2bfloat16(o1);
    *(__hip_bfloat162*)((__hip_bfloat16*)dout + (size_t)n*128 + c0) = o2;
  } else {
    float2 o2; o2.x = o0; o2.y = o1;
    *(float2*)((float*)dout + (size_t)n*128 + c0) = o2;
  }
}

// ---- layer-2 aggregate, 1 wave/node, 1 channel/lane
__global__ __launch_bounds__(256) void agg2(const float* __restrict__ h2,
    const float* __restrict__ as2, const float* __restrict__ ad2,
    const int* __restrict__ rowp, const int* __restrict__ csr,
    const float* __restrict__ bias2f,
    const int* __restrict__ flag, void* __restrict__ dout, int nn, int Etot){
  int f32 = *flag;
  int w = threadIdx.x >> 6, lane = threadIdx.x & 63;
  int n = blockIdx.x*4 + w;
  if (n >= nn) return;
  float adst = ad2[n];
  float e0 = fminf(lrelu(as2[n] + adst), 30.f);
  float wgt = __expf(e0);
  float acc = wgt * h2[(size_t)n*64 + lane];
  float den = wgt;
  int p = rowp[n], pe = rowp[n+1];
  if (p < 0) p = 0; if (pe > Etot) pe = Etot;
  for (; p < pe; ++p){
    int s = csr[p];
    if ((unsigned)s >= (unsigned)nn) continue;
    float ev = fminf(lrelu(as2[s] + adst), 30.f);
    float wv = __expf(ev);
    acc += wv * h2[(size_t)s*64 + lane];
    den += wv;
  }
  float o = acc/(den + 1e-16f) + bias2f[lane];
  size_t ofs = (size_t)nn*128 + (size_t)n*64 + lane;
  if (!f32) ((__hip_bfloat16*)dout)[ofs] = __float2bfloat16(o);
  else      ((float*)dout)[ofs] = o;
}

extern "C" void kernel_launch(void* const* d_in, const int* in_sizes, int n_in,
                              void* d_out, int out_size, void* d_ws, size_t ws_size,
                              hipStream_t stream){
  (void)n_in; (void)out_size; (void)ws_size;
  const void* x     = d_in[0];
  const int*  ei    = (const int*)d_in[1];
  const void* W1    = d_in[2];
  const void* a1s   = d_in[3];
  const void* a1d   = d_in[4];
  const void* b1    = d_in[5];
  const void* resW  = d_in[6];
  const void* g     = d_in[7];
  const void* bt    = d_in[8];
  const void* W2    = d_in[9];
  const void* a2s   = d_in[10];
  const void* a2d   = d_in[11];
  const void* b2    = d_in[12];

  int N = in_sizes[0] / 128;
  int E = in_sizes[1] / 2;

  // ---- compact workspace layout (~39.3 MB total) ----
  char* ws = (char*)d_ws;
  size_t o = 0;
  auto alloc = [&](size_t bytes)->char*{ char* r = ws + o; o = (o + bytes + 255) & ~(size_t)255; return r; };
  int*   flag = (int*)  alloc(4);
  int*   part = (int*)  alloc(4096);
  int*   rowp = (int*)  alloc(((size_t)N+1)*4);
  int*   cnt  = (int*)  alloc((size_t)N*4);
  float* as1  = (float*)alloc((size_t)N*8*4);
  float* ad1  = (float*)alloc((size_t)N*8*4);
  int*   csr  = (int*)  alloc((size_t)E*4);
  __hip_bfloat16* h1b = (__hip_bfloat16*)alloc((size_t)N*128*2);  // h2 fp32 [N,64] aliases (same bytes)
  __hip_bfloat16* Bt1   = (__hip_bfloat16*)alloc(32768);
  __hip_bfloat16* W2t   = (__hip_bfloat16*)alloc(16384);
  __hip_bfloat16* resWc = (__hip_bfloat16*)alloc(32768);
  float* att1s  = (float*)alloc(512);
  float* att1d  = (float*)alloc(512);
  float* bias1f = (float*)alloc(512);
  float* gfv    = (float*)alloc(512);
  float* bfv    = (float*)alloc(512);
  float* att2s  = (float*)alloc(256);
  float* att2d  = (float*)alloc(256);
  float* bias2f = (float*)alloc(256);
  float* h2  = (float*)h1b;   // alias: h1 dead after agg1; N*128*2 == N*64*4 bytes
  float* as2 = as1;           // alias: dead after agg1
  float* ad2 = ad1;

  int EB = (E + 255)/256;
  int NB = (N + 1023)/1024;

  (void)hipMemsetAsync(flag, 0, 4, stream);
  (void)hipMemsetAsync(cnt,  0, (size_t)N*4, stream);
  detect<<<16, 256, 0, stream>>>((const unsigned short*)x, flag);
  prep<<<164, 256, 0, stream>>>(W1, resW, W2, a1s, a1d, b1, g, bt, a2s, a2d, b2,
                                Bt1, W2t, resWc, att1s, att1d, bias1f, gfv, bfv,
                                att2s, att2d, bias2f, flag);
  gemm1<<<(N+15)/16, 256, 0, stream>>>(x, Bt1, h1b, flag, N);
  count_edges<<<EB, 256, 0, stream>>>(ei, cnt, E, N);
  scan_part<<<NB, 256, 0, stream>>>(cnt, part, N);
  scan_mid<<<1, 256, 0, stream>>>(part, NB, rowp, N);
  scan_write<<<NB, 256, 0, stream>>>(cnt, part, rowp, N);
  (void)hipMemsetAsync(cnt, 0, (size_t)N*4, stream);
  fill_csr<<<EB, 256, 0, stream>>>(ei, rowp, cnt, csr, E, N);
  attdot1<<<(N*8 + 255)/256, 256, 0, stream>>>(h1b, att1s, att1d, as1, ad1, N);
  agg1<<<(N+3)/4, 256, 0, stream>>>(h1b, as1, ad1, rowp, csr, x, resWc,
                                    bias1f, gfv, bfv, flag, d_out, N, E);
  gemm2<<<(N+15)/16, 256, 0, stream>>>(d_out, W2t, h2, flag, N);
  attdot2<<<(N+255)/256, 256, 0, stream>>>(h2, att2s, att2d, as2, ad2, N);
  agg2<<<(N+3)/4, 256, 0, stream>>>(h2, as2, ad2, rowp, csr, bias2f, flag, d_out, N, E);
}

// Round 3
// 877.841 us; speedup vs baseline: 1.1972x; 1.1972x over previous
//
#include <hip/hip_runtime.h>
#include <hip/hip_bf16.h>

typedef __attribute__((ext_vector_type(8))) short bf16x8;
typedef __attribute__((ext_vector_type(4))) float f32x4;

__device__ __forceinline__ float bfu(unsigned short u){
  union{ unsigned int i; float f; } c; c.i = ((unsigned)u) << 16; return c.f;
}
__device__ __forceinline__ float ldval(const void* p, int i, int f32){
  return f32 ? ((const float*)p)[i] : bfu(((const unsigned short*)p)[i]);
}
__device__ __forceinline__ bf16x8 packbf8(float4 u, float4 v){
  union { bf16x8 v8; __hip_bfloat16 h[8]; } r;
  r.h[0]=__float2bfloat16(u.x); r.h[1]=__float2bfloat16(u.y);
  r.h[2]=__float2bfloat16(u.z); r.h[3]=__float2bfloat16(u.w);
  r.h[4]=__float2bfloat16(v.x); r.h[5]=__float2bfloat16(v.y);
  r.h[6]=__float2bfloat16(v.z); r.h[7]=__float2bfloat16(v.w);
  return r.v8;
}
__device__ __forceinline__ float lrelu(float v){ return v > 0.f ? v : 0.2f*v; }

// ---- dtype detect: fp32 data read as bf16 has wild exponents
__global__ void detect(const unsigned short* __restrict__ xh, int* __restrict__ flag){
  int i = blockIdx.x*256 + threadIdx.x;
  float v = fabsf(bfu(xh[i]));
  if (v > 1e4f) atomicOr(flag, 1);
}

// ---- canonicalize weights
__global__ void prep(const void* W1, const void* resW, const void* W2,
                     const void* a1s, const void* a1d, const void* b1,
                     const void* g, const void* bt,
                     const void* a2s, const void* a2d, const void* b2,
                     __hip_bfloat16* __restrict__ Bt1, __hip_bfloat16* __restrict__ W2t,
                     __hip_bfloat16* __restrict__ resWc,
                     float* att1s, float* att1d, float* bias1f, float* gf, float* bfta,
                     float* att2s, float* att2d, float* bias2f, const int* flag){
  int f = *flag;
  int idx = blockIdx.x*256 + threadIdx.x;
  if (idx < 16384){ int c=idx>>7, k=idx&127; Bt1[idx]  = __float2bfloat16(ldval(W1,  k*128+c, f)); }
  else if (idx < 24576){ int i=idx-16384, c=i>>7, k=i&127; W2t[i]  = __float2bfloat16(ldval(W2,  k*64+c,  f)); }
  else if (idx < 40960){ int i=idx-24576, c=i>>7, k=i&127; resWc[i]= __float2bfloat16(ldval(resW,k*128+c, f)); }
  else if (idx < 41088) att1s [idx-40960] = ldval(a1s, idx-40960, f);
  else if (idx < 41216) att1d [idx-41088] = ldval(a1d, idx-41088, f);
  else if (idx < 41344) bias1f[idx-41216] = ldval(b1,  idx-41216, f);
  else if (idx < 41472) gf    [idx-41344] = ldval(g,   idx-41344, f);
  else if (idx < 41600) bfta  [idx-41472] = ldval(bt,  idx-41472, f);
  else if (idx < 41664) att2s [idx-41600] = ldval(a2s, idx-41600, f);
  else if (idx < 41728) att2d [idx-41664] = ldval(a2d, idx-41664, f);
  else if (idx < 41792) bias2f[idx-41728] = ldval(b2,  idx-41728, f);
}

// ---- GEMM1: h1b[N,128] = bf16(x @ W1)
__global__ __launch_bounds__(256) void gemm1(const void* __restrict__ xp,
                  const __hip_bfloat16* __restrict__ Bt1,
                  __hip_bfloat16* __restrict__ h1b, const int* __restrict__ flag, int nn){
  int f32 = *flag;
  int wave = threadIdx.x >> 6, lane = threadIdx.x & 63;
  int m = lane & 15, q = lane >> 4;
  int n0 = blockIdx.x * 16;
  int row = n0 + m; if (row >= nn) row = nn - 1;
  f32x4 acc[2];
  acc[0] = (f32x4){0.f,0.f,0.f,0.f}; acc[1] = (f32x4){0.f,0.f,0.f,0.f};
  #pragma unroll
  for (int kk=0; kk<4; ++kk){
    bf16x8 a;
    if (!f32) a = *(const bf16x8*)((const __hip_bfloat16*)xp + (size_t)row*128 + kk*32 + q*8);
    else { const float4* fp = (const float4*)((const float*)xp + (size_t)row*128 + kk*32 + q*8);
           a = packbf8(fp[0], fp[1]); }
    #pragma unroll
    for (int ct=0; ct<2; ++ct){
      int c = wave*32 + ct*16 + m;
      bf16x8 b = *(const bf16x8*)(Bt1 + (size_t)c*128 + kk*32 + q*8);
      acc[ct] = __builtin_amdgcn_mfma_f32_16x16x32_bf16(a, b, acc[ct], 0, 0, 0);
    }
  }
  #pragma unroll
  for (int ct=0; ct<2; ++ct){
    int c = wave*32 + ct*16 + m;
    #pragma unroll
    for (int i=0;i<4;++i){
      int r = n0 + q*4 + i;
      if (r < nn) h1b[(size_t)r*128 + c] = __float2bfloat16(acc[ct][i]);
    }
  }
}

// ---- GEMM2: h2b[N,64] = bf16( h @ W2 ), h read from d_out
__global__ __launch_bounds__(256) void gemm2(const void* __restrict__ hp,
                  const __hip_bfloat16* __restrict__ W2t,
                  __hip_bfloat16* __restrict__ h2b, const int* __restrict__ flag, int nn){
  int f32 = *flag;
  int wave = threadIdx.x >> 6, lane = threadIdx.x & 63;
  int m = lane & 15, q = lane >> 4;
  int n0 = blockIdx.x * 16;
  int row = n0 + m; if (row >= nn) row = nn - 1;
  f32x4 acc = (f32x4){0.f,0.f,0.f,0.f};
  #pragma unroll
  for (int kk=0; kk<4; ++kk){
    bf16x8 a;
    if (!f32) a = *(const bf16x8*)((const __hip_bfloat16*)hp + (size_t)row*128 + kk*32 + q*8);
    else { const float4* fp = (const float4*)((const float*)hp + (size_t)row*128 + kk*32 + q*8);
           a = packbf8(fp[0], fp[1]); }
    int c = wave*16 + m;
    bf16x8 b = *(const bf16x8*)(W2t + (size_t)c*128 + kk*32 + q*8);
    acc = __builtin_amdgcn_mfma_f32_16x16x32_bf16(a, b, acc, 0, 0, 0);
  }
  int c = wave*16 + m;
  #pragma unroll
  for (int i=0;i<4;++i){
    int r = n0 + q*4 + i;
    if (r < nn) h2b[(size_t)r*64 + c] = __float2bfloat16(acc[i]);
  }
}

// ---- attention dots
__global__ void attdot1(const __hip_bfloat16* __restrict__ h1b,
                        const float* __restrict__ att1s, const float* __restrict__ att1d,
                        float* __restrict__ as1, float* __restrict__ ad1, int nn){
  int gid = blockIdx.x*256 + threadIdx.x;
  if (gid >= nn*8) return;
  int node = gid >> 3, h = gid & 7;
  const bf16x8* hp = (const bf16x8*)(h1b + (size_t)node*128 + h*16);
  bf16x8 v0 = hp[0], v1 = hp[1];
  float s=0.f, d=0.f;
  #pragma unroll
  for (int j=0;j<8;++j){
    float a = bfu((unsigned short)v0[j]);
    s += a*att1s[h*16+j]; d += a*att1d[h*16+j];
  }
  #pragma unroll
  for (int j=0;j<8;++j){
    float a = bfu((unsigned short)v1[j]);
    s += a*att1s[h*16+8+j]; d += a*att1d[h*16+8+j];
  }
  as1[gid]=s; ad1[gid]=d;
}

__global__ void attdot2(const __hip_bfloat16* __restrict__ h2b,
                        const float* __restrict__ att2s, const float* __restrict__ att2d,
                        float* __restrict__ as2, float* __restrict__ ad2, int nn){
  int gid = blockIdx.x*256 + threadIdx.x;
  if (gid >= nn) return;
  const bf16x8* hp = (const bf16x8*)(h2b + (size_t)gid*64);
  float s=0.f, d=0.f;
  #pragma unroll
  for (int t=0;t<8;++t){
    bf16x8 v = hp[t];
    #pragma unroll
    for (int j=0;j<8;++j){
      float a = bfu((unsigned short)v[j]);
      s += a*att2s[t*8+j]; d += a*att2d[t*8+j];
    }
  }
  as2[gid]=s; ad2[gid]=d;
}

// ---- CSR build
__global__ void count_edges(const int* __restrict__ ei, int* __restrict__ cnt, int E, int nn){
  int e = blockIdx.x*256 + threadIdx.x;
  if (e < E){ int d = ei[E+e]; if ((unsigned)d < (unsigned)nn) atomicAdd(&cnt[d], 1); }
}

__global__ void scan_part(const int* __restrict__ cnt, int* __restrict__ part, int n){
  __shared__ int red[256];
  int t = threadIdx.x;
  int base = blockIdx.x*1024 + t*4;
  int s = 0;
  #pragma unroll
  for (int j=0;j<4;++j){ int i = base + j; if (i < n) s += cnt[i]; }
  red[t] = s; __syncthreads();
  for (int off=128; off>0; off>>=1){
    if (t < off) red[t] += red[t+off];
    __syncthreads();
  }
  if (t == 0) part[blockIdx.x] = red[0];
}

__global__ void scan_mid(int* __restrict__ part, int nb, int* __restrict__ row_ptr, int n){
  __shared__ int sd[256];
  int t = threadIdx.x;
  int v = (t < nb) ? part[t] : 0;
  sd[t] = v; __syncthreads();
  for (int off=1; off<256; off<<=1){
    int xv = (t >= off) ? sd[t-off] : 0;
    __syncthreads();
    sd[t] += xv;
    __syncthreads();
  }
  if (t < nb) part[t] = sd[t] - v;
  if (t == 0) row_ptr[n] = sd[255];
}

__global__ void scan_write(const int* __restrict__ cnt, const int* __restrict__ part,
                           int* __restrict__ row_ptr, int n){
  __shared__ int sd[256];
  int t = threadIdx.x;
  int base = blockIdx.x*1024 + t*4;
  int v0=0,v1=0,v2=0,v3=0;
  if (base   < n) v0 = cnt[base];
  if (base+1 < n) v1 = cnt[base+1];
  if (base+2 < n) v2 = cnt[base+2];
  if (base+3 < n) v3 = cnt[base+3];
  int s = v0+v1+v2+v3;
  sd[t] = s; __syncthreads();
  for (int off=1; off<256; off<<=1){
    int xv = (t >= off) ? sd[t-off] : 0;
    __syncthreads();
    sd[t] += xv;
    __syncthreads();
  }
  int run = part[blockIdx.x] + sd[t] - s;
  if (base   < n) row_ptr[base]   = run; run += v0;
  if (base+1 < n) row_ptr[base+1] = run; run += v1;
  if (base+2 < n) row_ptr[base+2] = run; run += v2;
  if (base+3 < n) row_ptr[base+3] = run;
}

__global__ void fill_csr(const int* __restrict__ ei, const int* __restrict__ row_ptr,
                         int* __restrict__ cur, int* __restrict__ csr, int E, int nn){
  int e = blockIdx.x*256 + threadIdx.x;
  if (e < E){
    int d = ei[E+e];
    if ((unsigned)d < (unsigned)nn){
      int pos = row_ptr[d] + atomicAdd(&cur[d], 1);
      if ((unsigned)pos < (unsigned)E) csr[pos] = ei[e];
    }
  }
}

// ---- layer-1 aggregate + residual + LayerNorm + ELU, 1 wave/node, batched-MLP gathers
__global__ __launch_bounds__(256) void agg1(
    const __hip_bfloat16* __restrict__ h1b,
    const float* __restrict__ as1, const float* __restrict__ ad1,
    const int* __restrict__ rowp, const int* __restrict__ csr,
    const void* __restrict__ xp, const __hip_bfloat16* __restrict__ resWc,
    const float* __restrict__ bias1f, const float* __restrict__ gf,
    const float* __restrict__ bfta,
    const int* __restrict__ flag, void* __restrict__ dout, int nn, int Etot){
  __shared__ float xs[4][128];
  int f32 = *flag;
  int w = threadIdx.x >> 6, lane = threadIdx.x & 63;
  int n = blockIdx.x*4 + w;
  if (n >= nn) return;
  if (!f32){
    ushort2 u = ((const ushort2*)((const unsigned short*)xp + (size_t)n*128))[lane];
    xs[w][lane*2] = bfu(u.x); xs[w][lane*2+1] = bfu(u.y);
  } else {
    float2 u = ((const float2*)((const float*)xp + (size_t)n*128))[lane];
    xs[w][lane*2] = u.x; xs[w][lane*2+1] = u.y;
  }
  int h = lane >> 3, c0 = lane*2;
  // residual: r = (x @ resW)[n, c0..c0+1]  (x row broadcast from LDS)
  float r0 = 0.f, r1 = 0.f;
  const bf16x8* ca = (const bf16x8*)(resWc + (size_t)c0*128);
  const bf16x8* cb = (const bf16x8*)(resWc + (size_t)(c0+1)*128);
  const float4* xsv = (const float4*)xs[w];
  #pragma unroll 4
  for (int kk=0; kk<16; ++kk){
    bf16x8 a = ca[kk], b = cb[kk];
    float4 x0 = xsv[kk*2], x1 = xsv[kk*2+1];
    float xv[8] = {x0.x,x0.y,x0.z,x0.w,x1.x,x1.y,x1.z,x1.w};
    #pragma unroll
    for (int j=0;j<8;++j){
      r0 += xv[j] * bfu((unsigned short)a[j]);
      r1 += xv[j] * bfu((unsigned short)b[j]);
    }
  }
  // softmax-weighted gather: self-loop + incoming edges, 8 gathers in flight
  float adst = ad1[n*8 + h];
  float e0 = fminf(lrelu(as1[n*8 + h] + adst), 30.f);
  float wgt = __expf(e0);
  unsigned hv0 = *(const unsigned*)(h1b + (size_t)n*128 + c0);
  float acc0 = wgt*bfu((unsigned short)(hv0 & 0xffff));
  float acc1 = wgt*bfu((unsigned short)(hv0 >> 16));
  float den = wgt;
  int p0 = rowp[n], pe = rowp[n+1];
  if (p0 < 0) p0 = 0; if (pe > Etot) pe = Etot;
  for (int base = p0; base < pe; base += 64){
    int nchunk = pe - base; if (nchunk > 64) nchunk = 64;
    int e = base + lane; if (e > pe-1) e = pe-1;
    int idx = csr[e];
    if ((unsigned)idx >= (unsigned)nn) idx = 0;
    for (int j = 0; j < nchunk; j += 8){
      float av[8]; unsigned hv[8]; float mk[8];
      #pragma unroll
      for (int u=0;u<8;++u){
        int jj = j+u;
        int s = __shfl(idx, jj & 63);
        mk[u] = (jj < nchunk) ? 1.f : 0.f;
        av[u] = as1[(size_t)s*8 + h];
        hv[u] = *(const unsigned*)(h1b + (size_t)s*128 + c0);
      }
      #pragma unroll
      for (int u=0;u<8;++u){
        float ev = fminf(lrelu(av[u] + adst), 30.f);
        float wv = __expf(ev) * mk[u];
        den  += wv;
        acc0 += wv * bfu((unsigned short)(hv[u] & 0xffff));
        acc1 += wv * bfu((unsigned short)(hv[u] >> 16));
      }
    }
  }
  float inv = 1.f/(den + 1e-16f);
  float o0 = acc0*inv + r0 + bias1f[c0];
  float o1 = acc1*inv + r1 + bias1f[c0+1];
  float s1 = o0 + o1, s2 = o0*o0 + o1*o1;
  #pragma unroll
  for (int off=32; off>0; off>>=1){
    s1 += __shfl_xor(s1, off);
    s2 += __shfl_xor(s2, off);
  }
  float mu  = s1 * (1.f/128.f);
  float var = s2 * (1.f/128.f) - mu*mu;
  float rstd = rsqrtf(var + 1e-5f);
  o0 = (o0 - mu)*rstd*gf[c0]   + bfta[c0];
  o1 = (o1 - mu)*rstd*gf[c0+1] + bfta[c0+1];
  o0 = o0 > 0.f ? o0 : __expf(o0) - 1.f;
  o1 = o1 > 0.f ? o1 : __expf(o1) - 1.f;
  if (!f32){
    __hip_bfloat162 o2; o2.x = __float2bfloat16(o0); o2.y = __float2bfloat16(o1);
    *(__hip_bfloat162*)((__hip_bfloat16*)dout + (size_t)n*128 + c0) = o2;
  } else {
    float2 o2; o2.x = o0; o2.y = o1;
    *(float2*)((float*)dout + (size_t)n*128 + c0) = o2;
  }
}

// ---- layer-2 aggregate, 1 wave/node, 1 ch/lane, batched-MLP gathers
__global__ __launch_bounds__(256) void agg2(const __hip_bfloat16* __restrict__ h2b,
    const float* __restrict__ as2, const float* __restrict__ ad2,
    const int* __restrict__ rowp, const int* __restrict__ csr,
    const float* __restrict__ bias2f,
    const int* __restrict__ flag, void* __restrict__ dout, int nn, int Etot){
  int f32 = *flag;
  int w = threadIdx.x >> 6, lane = threadIdx.x & 63;
  int n = blockIdx.x*4 + w;
  if (n >= nn) return;
  float adst = ad2[n];
  float e0 = fminf(lrelu(as2[n] + adst), 30.f);
  float wgt = __expf(e0);
  float acc = wgt * bfu(((const unsigned short*)h2b)[(size_t)n*64 + lane]);
  float den = wgt;
  int p0 = rowp[n], pe = rowp[n+1];
  if (p0 < 0) p0 = 0; if (pe > Etot) pe = Etot;
  for (int base = p0; base < pe; base += 64){
    int nchunk = pe - base; if (nchunk > 64) nchunk = 64;
    int e = base + lane; if (e > pe-1) e = pe-1;
    int idx = csr[e];
    if ((unsigned)idx >= (unsigned)nn) idx = 0;
    for (int j = 0; j < nchunk; j += 8){
      float av[8]; unsigned short hv[8]; float mk[8];
      #pragma unroll
      for (int u=0;u<8;++u){
        int jj = j+u;
        int s = __shfl(idx, jj & 63);
        mk[u] = (jj < nchunk) ? 1.f : 0.f;
        av[u] = as2[s];
        hv[u] = ((const unsigned short*)h2b)[(size_t)s*64 + lane];
      }
      #pragma unroll
      for (int u=0;u<8;++u){
        float ev = fminf(lrelu(av[u] + adst), 30.f);
        float wv = __expf(ev) * mk[u];
        den += wv;
        acc += wv * bfu(hv[u]);
      }
    }
  }
  float o = acc/(den + 1e-16f) + bias2f[lane];
  size_t ofs = (size_t)nn*128 + (size_t)n*64 + lane;
  if (!f32) ((__hip_bfloat16*)dout)[ofs] = __float2bfloat16(o);
  else      ((float*)dout)[ofs] = o;
}

extern "C" void kernel_launch(void* const* d_in, const int* in_sizes, int n_in,
                              void* d_out, int out_size, void* d_ws, size_t ws_size,
                              hipStream_t stream){
  (void)n_in; (void)out_size; (void)ws_size;
  const void* x     = d_in[0];
  const int*  ei    = (const int*)d_in[1];
  const void* W1    = d_in[2];
  const void* a1s   = d_in[3];
  const void* a1d   = d_in[4];
  const void* b1    = d_in[5];
  const void* resW  = d_in[6];
  const void* g     = d_in[7];
  const void* bt    = d_in[8];
  const void* W2    = d_in[9];
  const void* a2s   = d_in[10];
  const void* a2d   = d_in[11];
  const void* b2    = d_in[12];

  int N = in_sizes[0] / 128;
  int E = in_sizes[1] / 2;

  char* ws = (char*)d_ws;
  size_t o = 0;
  auto alloc = [&](size_t bytes)->char*{ char* r = ws + o; o = (o + bytes + 255) & ~(size_t)255; return r; };
  int*   flag = (int*)  alloc(4);
  int*   part = (int*)  alloc(4096);
  int*   rowp = (int*)  alloc(((size_t)N+1)*4);
  int*   cnt  = (int*)  alloc((size_t)N*4);
  float* as1  = (float*)alloc((size_t)N*8*4);
  float* ad1  = (float*)alloc((size_t)N*8*4);
  int*   csr  = (int*)  alloc((size_t)E*4);
  __hip_bfloat16* h1b = (__hip_bfloat16*)alloc((size_t)N*128*2);
  __hip_bfloat16* Bt1   = (__hip_bfloat16*)alloc(32768);
  __hip_bfloat16* W2t   = (__hip_bfloat16*)alloc(16384);
  __hip_bfloat16* resWc = (__hip_bfloat16*)alloc(32768);
  float* att1s  = (float*)alloc(512);
  float* att1d  = (float*)alloc(512);
  float* bias1f = (float*)alloc(512);
  float* gfv    = (float*)alloc(512);
  float* bfv    = (float*)alloc(512);
  float* att2s  = (float*)alloc(256);
  float* att2d  = (float*)alloc(256);
  float* bias2f = (float*)alloc(256);
  __hip_bfloat16* h2b = h1b;   // alias: h1b dead after agg1; needs N*64*2 <= N*128*2
  float* as2 = as1;            // alias: dead after agg1
  float* ad2 = ad1;

  int EB = (E + 255)/256;
  int NB = (N + 1023)/1024;

  (void)hipMemsetAsync(flag, 0, 4, stream);
  (void)hipMemsetAsync(cnt,  0, (size_t)N*4, stream);
  detect<<<16, 256, 0, stream>>>((const unsigned short*)x, flag);
  prep<<<164, 256, 0, stream>>>(W1, resW, W2, a1s, a1d, b1, g, bt, a2s, a2d, b2,
                                Bt1, W2t, resWc, att1s, att1d, bias1f, gfv, bfv,
                                att2s, att2d, bias2f, flag);
  gemm1<<<(N+15)/16, 256, 0, stream>>>(x, Bt1, h1b, flag, N);
  count_edges<<<EB, 256, 0, stream>>>(ei, cnt, E, N);
  scan_part<<<NB, 256, 0, stream>>>(cnt, part, N);
  scan_mid<<<1, 256, 0, stream>>>(part, NB, rowp, N);
  scan_write<<<NB, 256, 0, stream>>>(cnt, part, rowp, N);
  (void)hipMemsetAsync(cnt, 0, (size_t)N*4, stream);
  fill_csr<<<EB, 256, 0, stream>>>(ei, rowp, cnt, csr, E, N);
  attdot1<<<(N*8 + 255)/256, 256, 0, stream>>>(h1b, att1s, att1d, as1, ad1, N);
  agg1<<<(N+3)/4, 256, 0, stream>>>(h1b, as1, ad1, rowp, csr, x, resWc,
                                    bias1f, gfv, bfv, flag, d_out, N, E);
  gemm2<<<(N+15)/16, 256, 0, stream>>>(d_out, W2t, h2b, flag, N);
  attdot2<<<(N+255)/256, 256, 0, stream>>>(h2b, att2s, att2d, as2, ad2, N);
  agg2<<<(N+3)/4, 256, 0, stream>>>(h2b, as2, ad2, rowp, csr, bias2f, flag, d_out, N, E);
}

// Round 4
// 592.581 us; speedup vs baseline: 1.7735x; 1.4814x over previous
//
#include <hip/hip_runtime.h>
#include <hip/hip_bf16.h>

typedef __attribute__((ext_vector_type(8))) short bf16x8;
typedef __attribute__((ext_vector_type(4))) float f32x4;

__device__ __forceinline__ float bfu(unsigned short u){
  union{ unsigned int i; float f; } c; c.i = ((unsigned)u) << 16; return c.f;
}
__device__ __forceinline__ float ldval(const void* p, int i, int f32){
  return f32 ? ((const float*)p)[i] : bfu(((const unsigned short*)p)[i]);
}
__device__ __forceinline__ bf16x8 packbf8(float4 u, float4 v){
  union { bf16x8 v8; __hip_bfloat16 h[8]; } r;
  r.h[0]=__float2bfloat16(u.x); r.h[1]=__float2bfloat16(u.y);
  r.h[2]=__float2bfloat16(u.z); r.h[3]=__float2bfloat16(u.w);
  r.h[4]=__float2bfloat16(v.x); r.h[5]=__float2bfloat16(v.y);
  r.h[6]=__float2bfloat16(v.z); r.h[7]=__float2bfloat16(v.w);
  return r.v8;
}
__device__ __forceinline__ float lrelu(float v){ return v > 0.f ? v : 0.2f*v; }

// ---- dtype detect: fp32 data read as bf16 has wild exponents
__global__ void detect(const unsigned short* __restrict__ xh, int* __restrict__ flag){
  int i = blockIdx.x*256 + threadIdx.x;
  float v = fabsf(bfu(xh[i]));
  if (v > 1e4f) atomicOr(flag, 1);
}

// ---- canonicalize weights: Bt1[256][128] = [W1 | resW]^T, W2t[64][128] = W2^T, smalls fp32
__global__ void prep(const void* W1, const void* resW, const void* W2,
                     const void* a1s, const void* a1d, const void* b1,
                     const void* g, const void* bt,
                     const void* a2s, const void* a2d, const void* b2,
                     __hip_bfloat16* __restrict__ Bt1, __hip_bfloat16* __restrict__ W2t,
                     float* att1s, float* att1d, float* bias1f, float* gf, float* bfta,
                     float* att2s, float* att2d, float* bias2f, const int* flag){
  int f = *flag;
  int idx = blockIdx.x*256 + threadIdx.x;
  if (idx < 16384){ int c=idx>>7, k=idx&127; Bt1[idx] = __float2bfloat16(ldval(W1,  k*128+c, f)); }
  else if (idx < 32768){ int i=idx-16384, c=i>>7, k=i&127; Bt1[idx] = __float2bfloat16(ldval(resW,k*128+c, f)); }
  else if (idx < 40960){ int i=idx-32768, c=i>>7, k=i&127; W2t[i]  = __float2bfloat16(ldval(W2,  k*64+c,  f)); }
  else if (idx < 41088) att1s [idx-40960] = ldval(a1s, idx-40960, f);
  else if (idx < 41216) att1d [idx-41088] = ldval(a1d, idx-41088, f);
  else if (idx < 41344) bias1f[idx-41216] = ldval(b1,  idx-41216, f);
  else if (idx < 41472) gf    [idx-41344] = ldval(g,   idx-41344, f);
  else if (idx < 41600) bfta  [idx-41472] = ldval(bt,  idx-41472, f);
  else if (idx < 41664) att2s [idx-41600] = ldval(a2s, idx-41600, f);
  else if (idx < 41728) att2d [idx-41664] = ldval(a2d, idx-41664, f);
  else if (idx < 41792) bias2f[idx-41728] = ldval(b2,  idx-41728, f);
}

// ---- GEMM1: [h1 | xres] = x[N,128] @ [W1|resW]; h1->ws bf16, xres->d_out scratch bf16
__global__ __launch_bounds__(256) void gemm1(const void* __restrict__ xp,
                  const __hip_bfloat16* __restrict__ Bt1,
                  __hip_bfloat16* __restrict__ h1b,
                  __hip_bfloat16* __restrict__ xrB,   // bf16-output case scratch
                  __hip_bfloat16* __restrict__ xrF,   // fp32-output case scratch
                  const int* __restrict__ flag, int nn){
  int f32 = *flag;
  __hip_bfloat16* xr = f32 ? xrF : xrB;
  int wave = threadIdx.x >> 6, lane = threadIdx.x & 63;
  int m = lane & 15, q = lane >> 4;
  int n0 = blockIdx.x * 16;
  int row = n0 + m; if (row >= nn) row = nn - 1;
  f32x4 acc[4];
  #pragma unroll
  for (int ct=0; ct<4; ++ct) acc[ct] = (f32x4){0.f,0.f,0.f,0.f};
  #pragma unroll
  for (int kk=0; kk<4; ++kk){
    bf16x8 a;
    if (!f32) a = *(const bf16x8*)((const __hip_bfloat16*)xp + (size_t)row*128 + kk*32 + q*8);
    else { const float4* fp = (const float4*)((const float*)xp + (size_t)row*128 + kk*32 + q*8);
           a = packbf8(fp[0], fp[1]); }
    #pragma unroll
    for (int ct=0; ct<4; ++ct){
      int c = wave*64 + ct*16 + m;
      bf16x8 b = *(const bf16x8*)(Bt1 + (size_t)c*128 + kk*32 + q*8);
      acc[ct] = __builtin_amdgcn_mfma_f32_16x16x32_bf16(a, b, acc[ct], 0, 0, 0);
    }
  }
  #pragma unroll
  for (int ct=0; ct<4; ++ct){
    int c = wave*64 + ct*16 + m;
    #pragma unroll
    for (int i=0;i<4;++i){
      int r = n0 + q*4 + i;
      if (r < nn){
        float v = acc[ct][i];
        if (c < 128) h1b[(size_t)r*128 + c] = __float2bfloat16(v);
        else         xr [(size_t)r*128 + (c-128)] = __float2bfloat16(v);
      }
    }
  }
}

// ---- GEMM2: h2b[N,64] = bf16( h @ W2 ), h read from d_out
__global__ __launch_bounds__(256) void gemm2(const void* __restrict__ hp,
                  const __hip_bfloat16* __restrict__ W2t,
                  __hip_bfloat16* __restrict__ h2b, const int* __restrict__ flag, int nn){
  int f32 = *flag;
  int wave = threadIdx.x >> 6, lane = threadIdx.x & 63;
  int m = lane & 15, q = lane >> 4;
  int n0 = blockIdx.x * 16;
  int row = n0 + m; if (row >= nn) row = nn - 1;
  f32x4 acc = (f32x4){0.f,0.f,0.f,0.f};
  #pragma unroll
  for (int kk=0; kk<4; ++kk){
    bf16x8 a;
    if (!f32) a = *(const bf16x8*)((const __hip_bfloat16*)hp + (size_t)row*128 + kk*32 + q*8);
    else { const float4* fp = (const float4*)((const float*)hp + (size_t)row*128 + kk*32 + q*8);
           a = packbf8(fp[0], fp[1]); }
    int c = wave*16 + m;
    bf16x8 b = *(const bf16x8*)(W2t + (size_t)c*128 + kk*32 + q*8);
    acc = __builtin_amdgcn_mfma_f32_16x16x32_bf16(a, b, acc, 0, 0, 0);
  }
  int c = wave*16 + m;
  #pragma unroll
  for (int i=0;i<4;++i){
    int r = n0 + q*4 + i;
    if (r < nn) h2b[(size_t)r*64 + c] = __float2bfloat16(acc[i]);
  }
}

// ---- attention dots
__global__ void attdot1(const __hip_bfloat16* __restrict__ h1b,
                        const float* __restrict__ att1s, const float* __restrict__ att1d,
                        float* __restrict__ as1, float* __restrict__ ad1, int nn){
  int gid = blockIdx.x*256 + threadIdx.x;
  if (gid >= nn*8) return;
  int node = gid >> 3, h = gid & 7;
  const bf16x8* hp = (const bf16x8*)(h1b + (size_t)node*128 + h*16);
  bf16x8 v0 = hp[0], v1 = hp[1];
  float s=0.f, d=0.f;
  #pragma unroll
  for (int j=0;j<8;++j){
    float a = bfu((unsigned short)v0[j]);
    s += a*att1s[h*16+j]; d += a*att1d[h*16+j];
  }
  #pragma unroll
  for (int j=0;j<8;++j){
    float a = bfu((unsigned short)v1[j]);
    s += a*att1s[h*16+8+j]; d += a*att1d[h*16+8+j];
  }
  as1[gid]=s; ad1[gid]=d;
}

__global__ void attdot2(const __hip_bfloat16* __restrict__ h2b,
                        const float* __restrict__ att2s, const float* __restrict__ att2d,
                        float* __restrict__ as2, float* __restrict__ ad2, int nn){
  int gid = blockIdx.x*256 + threadIdx.x;
  if (gid >= nn) return;
  const bf16x8* hp = (const bf16x8*)(h2b + (size_t)gid*64);
  float s=0.f, d=0.f;
  #pragma unroll
  for (int t=0;t<8;++t){
    bf16x8 v = hp[t];
    #pragma unroll
    for (int j=0;j<8;++j){
      float a = bfu((unsigned short)v[j]);
      s += a*att2s[t*8+j]; d += a*att2d[t*8+j];
    }
  }
  as2[gid]=s; ad2[gid]=d;
}

// ---- CSR build
__global__ void count_edges(const int* __restrict__ ei, int* __restrict__ cnt, int E, int nn){
  int e = blockIdx.x*256 + threadIdx.x;
  if (e < E){ int d = ei[E+e]; if ((unsigned)d < (unsigned)nn) atomicAdd(&cnt[d], 1); }
}

__global__ void scan_part(const int* __restrict__ cnt, int* __restrict__ part, int n){
  __shared__ int red[256];
  int t = threadIdx.x;
  int base = blockIdx.x*1024 + t*4;
  int s = 0;
  #pragma unroll
  for (int j=0;j<4;++j){ int i = base + j; if (i < n) s += cnt[i]; }
  red[t] = s; __syncthreads();
  for (int off=128; off>0; off>>=1){
    if (t < off) red[t] += red[t+off];
    __syncthreads();
  }
  if (t == 0) part[blockIdx.x] = red[0];
}

__global__ void scan_mid(int* __restrict__ part, int nb, int* __restrict__ row_ptr, int n){
  __shared__ int sd[256];
  int t = threadIdx.x;
  int v = (t < nb) ? part[t] : 0;
  sd[t] = v; __syncthreads();
  for (int off=1; off<256; off<<=1){
    int xv = (t >= off) ? sd[t-off] : 0;
    __syncthreads();
    sd[t] += xv;
    __syncthreads();
  }
  if (t < nb) part[t] = sd[t] - v;
  if (t == 0) row_ptr[n] = sd[255];
}

__global__ void scan_write(const int* __restrict__ cnt, const int* __restrict__ part,
                           int* __restrict__ row_ptr, int n){
  __shared__ int sd[256];
  int t = threadIdx.x;
  int base = blockIdx.x*1024 + t*4;
  int v0=0,v1=0,v2=0,v3=0;
  if (base   < n) v0 = cnt[base];
  if (base+1 < n) v1 = cnt[base+1];
  if (base+2 < n) v2 = cnt[base+2];
  if (base+3 < n) v3 = cnt[base+3];
  int s = v0+v1+v2+v3;
  sd[t] = s; __syncthreads();
  for (int off=1; off<256; off<<=1){
    int xv = (t >= off) ? sd[t-off] : 0;
    __syncthreads();
    sd[t] += xv;
    __syncthreads();
  }
  int run = part[blockIdx.x] + sd[t] - s;
  if (base   < n) row_ptr[base]   = run; run += v0;
  if (base+1 < n) row_ptr[base+1] = run; run += v1;
  if (base+2 < n) row_ptr[base+2] = run; run += v2;
  if (base+3 < n) row_ptr[base+3] = run;
}

__global__ void fill_csr(const int* __restrict__ ei, const int* __restrict__ row_ptr,
                         int* __restrict__ cur, int* __restrict__ csr, int E, int nn){
  int e = blockIdx.x*256 + threadIdx.x;
  if (e < E){
    int d = ei[E+e];
    if ((unsigned)d < (unsigned)nn){
      int pos = row_ptr[d] + atomicAdd(&cur[d], 1);
      if ((unsigned)pos < (unsigned)E) csr[pos] = ei[e];
    }
  }
}

// ---- layer-1 aggregate + xres + LayerNorm + ELU; 1 wave/node; scalar-indexed 16-deep gathers
__global__ __launch_bounds__(256) void agg1(
    const __hip_bfloat16* __restrict__ h1b,
    const float* __restrict__ as1, const float* __restrict__ ad1,
    const int* __restrict__ rowp, const int* __restrict__ csr,
    const __hip_bfloat16* __restrict__ xrB, const __hip_bfloat16* __restrict__ xrF,
    const float* __restrict__ bias1f, const float* __restrict__ gf,
    const float* __restrict__ bfta,
    const int* __restrict__ flag, void* __restrict__ dout, int nn, int Etot){
  int f32 = *flag;
  int w = threadIdx.x >> 6, lane = threadIdx.x & 63;
  int n = blockIdx.x*4 + w;
  if (n >= nn) return;
  int h = lane >> 3, c0 = lane*2;
  // independent early loads
  const __hip_bfloat16* xr = f32 ? xrF : xrB;
  ushort2 xru = ((const ushort2*)(xr))[(size_t)n*64 + lane];
  float adst = ad1[n*8 + h];
  float asn  = as1[n*8 + h];
  unsigned hv0 = *(const unsigned*)(h1b + (size_t)n*128 + c0);
  int p0 = rowp[n], pe = rowp[n+1];
  if (p0 < 0) p0 = 0; if (pe > Etot) pe = Etot;
  int p0u = __builtin_amdgcn_readfirstlane(p0);
  int peu = __builtin_amdgcn_readfirstlane(pe);
  // self-loop
  float e0 = fminf(lrelu(asn + adst), 30.f);
  float wgt = __expf(e0);
  float acc0 = wgt*bfu((unsigned short)(hv0 & 0xffff));
  float acc1 = wgt*bfu((unsigned short)(hv0 >> 16));
  float den = wgt;
  for (int base = p0u; base < peu; base += 64){
    int lim = peu - base; if (lim > 64) lim = 64;
    for (int j = 0; j < lim; j += 16){
      float av[16]; unsigned hv[16];
      #pragma unroll
      for (int u=0;u<16;++u){
        int jj = j+u;
        int jp = jj < lim ? jj : lim-1;
        int s = csr[base + jp];                 // uniform addr -> s_load; s in SGPR
        av[u] = as1[(size_t)s*8 + h];           // saddr gather, voffset h*4
        hv[u] = *(const unsigned*)(h1b + (size_t)s*128 + c0);  // saddr gather, voffset lane*4
      }
      #pragma unroll
      for (int u=0;u<16;++u){
        int jj = j+u;
        float mk = (jj < lim) ? 1.f : 0.f;
        float ev = fminf(lrelu(av[u] + adst), 30.f);
        float wv = __expf(ev) * mk;
        den  += wv;
        acc0 += wv * bfu((unsigned short)(hv[u] & 0xffff));
        acc1 += wv * bfu((unsigned short)(hv[u] >> 16));
      }
    }
  }
  float inv = 1.f/(den + 1e-16f);
  float o0 = acc0*inv + bfu(xru.x) + bias1f[c0];
  float o1 = acc1*inv + bfu(xru.y) + bias1f[c0+1];
  float s1 = o0 + o1, s2 = o0*o0 + o1*o1;
  #pragma unroll
  for (int off=32; off>0; off>>=1){
    s1 += __shfl_xor(s1, off);
    s2 += __shfl_xor(s2, off);
  }
  float mu  = s1 * (1.f/128.f);
  float var = s2 * (1.f/128.f) - mu*mu;
  float rstd = rsqrtf(var + 1e-5f);
  o0 = (o0 - mu)*rstd*gf[c0]   + bfta[c0];
  o1 = (o1 - mu)*rstd*gf[c0+1] + bfta[c0+1];
  o0 = o0 > 0.f ? o0 : __expf(o0) - 1.f;
  o1 = o1 > 0.f ? o1 : __expf(o1) - 1.f;
  if (!f32){
    __hip_bfloat162 o2; o2.x = __float2bfloat16(o0); o2.y = __float2bfloat16(o1);
    *(__hip_bfloat162*)((__hip_bfloat16*)dout + (size_t)n*128 + c0) = o2;
  } else {
    float2 o2; o2.x = o0; o2.y = o1;
    *(float2*)((float*)dout + (size_t)n*128 + c0) = o2;
  }
}

// ---- layer-2 aggregate; 1 wave/node, 1 ch/lane; scalar-indexed 16-deep gathers
__global__ __launch_bounds__(256) void agg2(const __hip_bfloat16* __restrict__ h2b,
    const float* __restrict__ as2, const float* __restrict__ ad2,
    const int* __restrict__ rowp, const int* __restrict__ csr,
    const float* __restrict__ bias2f,
    const int* __restrict__ flag, void* __restrict__ dout, int nn, int Etot){
  int f32 = *flag;
  int w = threadIdx.x >> 6, lane = threadIdx.x & 63;
  int n = blockIdx.x*4 + w;
  if (n >= nn) return;
  float adst = ad2[n];
  float e0 = fminf(lrelu(as2[n] + adst), 30.f);
  float wgt = __expf(e0);
  float acc = wgt * bfu(((const unsigned short*)h2b)[(size_t)n*64 + lane]);
  float den = wgt;
  int p0 = rowp[n], pe = rowp[n+1];
  if (p0 < 0) p0 = 0; if (pe > Etot) pe = Etot;
  int p0u = __builtin_amdgcn_readfirstlane(p0);
  int peu = __builtin_amdgcn_readfirstlane(pe);
  for (int base = p0u; base < peu; base += 64){
    int lim = peu - base; if (lim > 64) lim = 64;
    for (int j = 0; j < lim; j += 16){
      float av[16]; unsigned short hv[16];
      #pragma unroll
      for (int u=0;u<16;++u){
        int jj = j+u;
        int jp = jj < lim ? jj : lim-1;
        int s = csr[base + jp];
        av[u] = as2[s];
        hv[u] = ((const unsigned short*)h2b)[(size_t)s*64 + lane];
      }
      #pragma unroll
      for (int u=0;u<16;++u){
        int jj = j+u;
        float mk = (jj < lim) ? 1.f : 0.f;
        float ev = fminf(lrelu(av[u] + adst), 30.f);
        float wv = __expf(ev) * mk;
        den += wv;
        acc += wv * bfu(hv[u]);
      }
    }
  }
  float o = acc/(den + 1e-16f) + bias2f[lane];
  size_t ofs = (size_t)nn*128 + (size_t)n*64 + lane;
  if (!f32) ((__hip_bfloat16*)dout)[ofs] = __float2bfloat16(o);
  else      ((float*)dout)[ofs] = o;
}

extern "C" void kernel_launch(void* const* d_in, const int* in_sizes, int n_in,
                              void* d_out, int out_size, void* d_ws, size_t ws_size,
                              hipStream_t stream){
  (void)n_in; (void)out_size; (void)ws_size;
  const void* x     = d_in[0];
  const int*  ei    = (const int*)d_in[1];
  const void* W1    = d_in[2];
  const void* a1s   = d_in[3];
  const void* a1d   = d_in[4];
  const void* b1    = d_in[5];
  const void* resW  = d_in[6];
  const void* g     = d_in[7];
  const void* bt    = d_in[8];
  const void* W2    = d_in[9];
  const void* a2s   = d_in[10];
  const void* a2d   = d_in[11];
  const void* b2    = d_in[12];

  int N = in_sizes[0] / 128;
  int E = in_sizes[1] / 2;

  // xres scratch lives inside d_out (no extra ws):
  //  - bf16-output case: the h region itself (same offsets, same-wave read-then-write)
  //  - fp32-output case: the logits float region (N*64*4 B == N*128*2 B), read before agg2 writes
  __hip_bfloat16* xrB = (__hip_bfloat16*)d_out;
  __hip_bfloat16* xrF = (__hip_bfloat16*)((float*)d_out + (size_t)N*128);

  char* ws = (char*)d_ws;
  size_t o = 0;
  auto alloc = [&](size_t bytes)->char*{ char* r = ws + o; o = (o + bytes + 255) & ~(size_t)255; return r; };
  int*   flag = (int*)  alloc(4);
  int*   part = (int*)  alloc(4096);
  int*   rowp = (int*)  alloc(((size_t)N+1)*4);
  int*   cnt  = (int*)  alloc((size_t)N*4);
  float* as1  = (float*)alloc((size_t)N*8*4);
  float* ad1  = (float*)alloc((size_t)N*8*4);
  int*   csr  = (int*)  alloc((size_t)E*4);
  __hip_bfloat16* h1b = (__hip_bfloat16*)alloc((size_t)N*128*2);
  __hip_bfloat16* Bt1 = (__hip_bfloat16*)alloc(65536);   // [W1|resW]^T, 256x128
  __hip_bfloat16* W2t = (__hip_bfloat16*)alloc(16384);
  float* att1s  = (float*)alloc(512);
  float* att1d  = (float*)alloc(512);
  float* bias1f = (float*)alloc(512);
  float* gfv    = (float*)alloc(512);
  float* bfv    = (float*)alloc(512);
  float* att2s  = (float*)alloc(256);
  float* att2d  = (float*)alloc(256);
  float* bias2f = (float*)alloc(256);
  __hip_bfloat16* h2b = h1b;   // alias: h1b dead after agg1
  float* as2 = as1;            // alias: dead after agg1
  float* ad2 = ad1;

  int EB = (E + 255)/256;
  int NB = (N + 1023)/1024;

  (void)hipMemsetAsync(flag, 0, 4, stream);
  (void)hipMemsetAsync(cnt,  0, (size_t)N*4, stream);
  detect<<<16, 256, 0, stream>>>((const unsigned short*)x, flag);
  prep<<<164, 256, 0, stream>>>(W1, resW, W2, a1s, a1d, b1, g, bt, a2s, a2d, b2,
                                Bt1, W2t, att1s, att1d, bias1f, gfv, bfv,
                                att2s, att2d, bias2f, flag);
  gemm1<<<(N+15)/16, 256, 0, stream>>>(x, Bt1, h1b, xrB, xrF, flag, N);
  count_edges<<<EB, 256, 0, stream>>>(ei, cnt, E, N);
  scan_part<<<NB, 256, 0, stream>>>(cnt, part, N);
  scan_mid<<<1, 256, 0, stream>>>(part, NB, rowp, N);
  scan_write<<<NB, 256, 0, stream>>>(cnt, part, rowp, N);
  (void)hipMemsetAsync(cnt, 0, (size_t)N*4, stream);
  fill_csr<<<EB, 256, 0, stream>>>(ei, rowp, cnt, csr, E, N);
  attdot1<<<(N*8 + 255)/256, 256, 0, stream>>>(h1b, att1s, att1d, as1, ad1, N);
  agg1<<<(N+3)/4, 256, 0, stream>>>(h1b, as1, ad1, rowp, csr, xrB, xrF,
                                    bias1f, gfv, bfv, flag, d_out, N, E);
  gemm2<<<(N+15)/16, 256, 0, stream>>>(d_out, W2t, h2b, flag, N);
  attdot2<<<(N+255)/256, 256, 0, stream>>>(h2b, att2s, att2d, as2, ad2, N);
  agg2<<<(N+3)/4, 256, 0, stream>>>(h2b, as2, ad2, rowp, csr, bias2f, flag, d_out, N, E);
}

// Round 5
// 557.777 us; speedup vs baseline: 1.8841x; 1.0624x over previous
//
#include <hip/hip_runtime.h>
#include <hip/hip_bf16.h>

typedef __attribute__((ext_vector_type(8))) short bf16x8;
typedef __attribute__((ext_vector_type(4))) float f32x4;

__device__ __forceinline__ float bfu(unsigned short u){
  union{ unsigned int i; float f; } c; c.i = ((unsigned)u) << 16; return c.f;
}
__device__ __forceinline__ float bflo(unsigned u){
  union{ unsigned int i; float f; } c; c.i = u << 16; return c.f;
}
__device__ __forceinline__ float bfhi(unsigned u){
  union{ unsigned int i; float f; } c; c.i = u & 0xffff0000u; return c.f;
}
__device__ __forceinline__ float ldval(const void* p, int i, int f32){
  return f32 ? ((const float*)p)[i] : bfu(((const unsigned short*)p)[i]);
}
__device__ __forceinline__ bf16x8 packbf8(float4 u, float4 v){
  union { bf16x8 v8; __hip_bfloat16 h[8]; } r;
  r.h[0]=__float2bfloat16(u.x); r.h[1]=__float2bfloat16(u.y);
  r.h[2]=__float2bfloat16(u.z); r.h[3]=__float2bfloat16(u.w);
  r.h[4]=__float2bfloat16(v.x); r.h[5]=__float2bfloat16(v.y);
  r.h[6]=__float2bfloat16(v.z); r.h[7]=__float2bfloat16(v.w);
  return r.v8;
}
__device__ __forceinline__ float lrelu(float v){ return v > 0.f ? v : 0.2f*v; }

// ---- dtype detect: fp32 data read as bf16 has wild exponents
__global__ void detect(const unsigned short* __restrict__ xh, int* __restrict__ flag){
  int i = blockIdx.x*256 + threadIdx.x;
  float v = fabsf(bfu(xh[i]));
  if (v > 1e4f) atomicOr(flag, 1);
}

// ---- canonicalize weights: Bt1[256][128] = [W1 | resW]^T, W2t[64][128] = W2^T, smalls fp32
__global__ void prep(const void* W1, const void* resW, const void* W2,
                     const void* a1s, const void* a1d, const void* b1,
                     const void* g, const void* bt,
                     const void* a2s, const void* a2d, const void* b2,
                     __hip_bfloat16* __restrict__ Bt1, __hip_bfloat16* __restrict__ W2t,
                     float* att1s, float* att1d, float* bias1f, float* gf, float* bfta,
                     float* att2s, float* att2d, float* bias2f, const int* flag){
  int f = *flag;
  int idx = blockIdx.x*256 + threadIdx.x;
  if (idx < 16384){ int c=idx>>7, k=idx&127; Bt1[idx] = __float2bfloat16(ldval(W1,  k*128+c, f)); }
  else if (idx < 32768){ int i=idx-16384, c=i>>7, k=i&127; Bt1[idx] = __float2bfloat16(ldval(resW,k*128+c, f)); }
  else if (idx < 40960){ int i=idx-32768, c=i>>7, k=i&127; W2t[i]  = __float2bfloat16(ldval(W2,  k*64+c,  f)); }
  else if (idx < 41088) att1s [idx-40960] = ldval(a1s, idx-40960, f);
  else if (idx < 41216) att1d [idx-41088] = ldval(a1d, idx-41088, f);
  else if (idx < 41344) bias1f[idx-41216] = ldval(b1,  idx-41216, f);
  else if (idx < 41472) gf    [idx-41344] = ldval(g,   idx-41344, f);
  else if (idx < 41600) bfta  [idx-41472] = ldval(bt,  idx-41472, f);
  else if (idx < 41664) att2s [idx-41600] = ldval(a2s, idx-41600, f);
  else if (idx < 41728) att2d [idx-41664] = ldval(a2d, idx-41664, f);
  else if (idx < 41792) bias2f[idx-41728] = ldval(b2,  idx-41728, f);
}

// ---- GEMM1: [h1 | xres] = x[N,128] @ [W1|resW]; h1->ws bf16, xres->d_out scratch bf16
__global__ __launch_bounds__(256) void gemm1(const void* __restrict__ xp,
                  const __hip_bfloat16* __restrict__ Bt1,
                  __hip_bfloat16* __restrict__ h1b,
                  __hip_bfloat16* __restrict__ xrB,
                  __hip_bfloat16* __restrict__ xrF,
                  const int* __restrict__ flag, int nn){
  int f32 = *flag;
  __hip_bfloat16* xr = f32 ? xrF : xrB;
  int wave = threadIdx.x >> 6, lane = threadIdx.x & 63;
  int m = lane & 15, q = lane >> 4;
  int n0 = blockIdx.x * 16;
  int row = n0 + m; if (row >= nn) row = nn - 1;
  f32x4 acc[4];
  #pragma unroll
  for (int ct=0; ct<4; ++ct) acc[ct] = (f32x4){0.f,0.f,0.f,0.f};
  #pragma unroll
  for (int kk=0; kk<4; ++kk){
    bf16x8 a;
    if (!f32) a = *(const bf16x8*)((const __hip_bfloat16*)xp + (size_t)row*128 + kk*32 + q*8);
    else { const float4* fp = (const float4*)((const float*)xp + (size_t)row*128 + kk*32 + q*8);
           a = packbf8(fp[0], fp[1]); }
    #pragma unroll
    for (int ct=0; ct<4; ++ct){
      int c = wave*64 + ct*16 + m;
      bf16x8 b = *(const bf16x8*)(Bt1 + (size_t)c*128 + kk*32 + q*8);
      acc[ct] = __builtin_amdgcn_mfma_f32_16x16x32_bf16(a, b, acc[ct], 0, 0, 0);
    }
  }
  #pragma unroll
  for (int ct=0; ct<4; ++ct){
    int c = wave*64 + ct*16 + m;
    #pragma unroll
    for (int i=0;i<4;++i){
      int r = n0 + q*4 + i;
      if (r < nn){
        float v = acc[ct][i];
        if (c < 128) h1b[(size_t)r*128 + c] = __float2bfloat16(v);
        else         xr [(size_t)r*128 + (c-128)] = __float2bfloat16(v);
      }
    }
  }
}

// ---- GEMM2: h2b[N,64] = bf16( h @ W2 ), h read from d_out
__global__ __launch_bounds__(256) void gemm2(const void* __restrict__ hp,
                  const __hip_bfloat16* __restrict__ W2t,
                  __hip_bfloat16* __restrict__ h2b, const int* __restrict__ flag, int nn){
  int f32 = *flag;
  int wave = threadIdx.x >> 6, lane = threadIdx.x & 63;
  int m = lane & 15, q = lane >> 4;
  int n0 = blockIdx.x * 16;
  int row = n0 + m; if (row >= nn) row = nn - 1;
  f32x4 acc = (f32x4){0.f,0.f,0.f,0.f};
  #pragma unroll
  for (int kk=0; kk<4; ++kk){
    bf16x8 a;
    if (!f32) a = *(const bf16x8*)((const __hip_bfloat16*)hp + (size_t)row*128 + kk*32 + q*8);
    else { const float4* fp = (const float4*)((const float*)hp + (size_t)row*128 + kk*32 + q*8);
           a = packbf8(fp[0], fp[1]); }
    int c = wave*16 + m;
    bf16x8 b = *(const bf16x8*)(W2t + (size_t)c*128 + kk*32 + q*8);
    acc = __builtin_amdgcn_mfma_f32_16x16x32_bf16(a, b, acc, 0, 0, 0);
  }
  int c = wave*16 + m;
  #pragma unroll
  for (int i=0;i<4;++i){
    int r = n0 + q*4 + i;
    if (r < nn) h2b[(size_t)r*64 + c] = __float2bfloat16(acc[i]);
  }
}

// ---- attention dots
__global__ void attdot1(const __hip_bfloat16* __restrict__ h1b,
                        const float* __restrict__ att1s, const float* __restrict__ att1d,
                        float* __restrict__ as1, float* __restrict__ ad1, int nn){
  int gid = blockIdx.x*256 + threadIdx.x;
  if (gid >= nn*8) return;
  int node = gid >> 3, h = gid & 7;
  const bf16x8* hp = (const bf16x8*)(h1b + (size_t)node*128 + h*16);
  bf16x8 v0 = hp[0], v1 = hp[1];
  float s=0.f, d=0.f;
  #pragma unroll
  for (int j=0;j<8;++j){
    float a = bfu((unsigned short)v0[j]);
    s += a*att1s[h*16+j]; d += a*att1d[h*16+j];
  }
  #pragma unroll
  for (int j=0;j<8;++j){
    float a = bfu((unsigned short)v1[j]);
    s += a*att1s[h*16+8+j]; d += a*att1d[h*16+8+j];
  }
  as1[gid]=s; ad1[gid]=d;
}

__global__ void attdot2(const __hip_bfloat16* __restrict__ h2b,
                        const float* __restrict__ att2s, const float* __restrict__ att2d,
                        float* __restrict__ as2, float* __restrict__ ad2, int nn){
  int gid = blockIdx.x*256 + threadIdx.x;
  if (gid >= nn) return;
  const bf16x8* hp = (const bf16x8*)(h2b + (size_t)gid*64);
  float s=0.f, d=0.f;
  #pragma unroll
  for (int t=0;t<8;++t){
    bf16x8 v = hp[t];
    #pragma unroll
    for (int j=0;j<8;++j){
      float a = bfu((unsigned short)v[j]);
      s += a*att2s[t*8+j]; d += a*att2d[t*8+j];
    }
  }
  as2[gid]=s; ad2[gid]=d;
}

// ---- CSR build
__global__ void count_edges(const int* __restrict__ ei, int* __restrict__ cnt, int E, int nn){
  int e = blockIdx.x*256 + threadIdx.x;
  if (e < E){ int d = ei[E+e]; if ((unsigned)d < (unsigned)nn) atomicAdd(&cnt[d], 1); }
}

__global__ void scan_part(const int* __restrict__ cnt, int* __restrict__ part, int n){
  __shared__ int red[256];
  int t = threadIdx.x;
  int base = blockIdx.x*1024 + t*4;
  int s = 0;
  #pragma unroll
  for (int j=0;j<4;++j){ int i = base + j; if (i < n) s += cnt[i]; }
  red[t] = s; __syncthreads();
  for (int off=128; off>0; off>>=1){
    if (t < off) red[t] += red[t+off];
    __syncthreads();
  }
  if (t == 0) part[blockIdx.x] = red[0];
}

__global__ void scan_mid(int* __restrict__ part, int nb, int* __restrict__ row_ptr, int n){
  __shared__ int sd[256];
  int t = threadIdx.x;
  int v = (t < nb) ? part[t] : 0;
  sd[t] = v; __syncthreads();
  for (int off=1; off<256; off<<=1){
    int xv = (t >= off) ? sd[t-off] : 0;
    __syncthreads();
    sd[t] += xv;
    __syncthreads();
  }
  if (t < nb) part[t] = sd[t] - v;
  if (t == 0) row_ptr[n] = sd[255];
}

__global__ void scan_write(const int* __restrict__ cnt, const int* __restrict__ part,
                           int* __restrict__ row_ptr, int n){
  __shared__ int sd[256];
  int t = threadIdx.x;
  int base = blockIdx.x*1024 + t*4;
  int v0=0,v1=0,v2=0,v3=0;
  if (base   < n) v0 = cnt[base];
  if (base+1 < n) v1 = cnt[base+1];
  if (base+2 < n) v2 = cnt[base+2];
  if (base+3 < n) v3 = cnt[base+3];
  int s = v0+v1+v2+v3;
  sd[t] = s; __syncthreads();
  for (int off=1; off<256; off<<=1){
    int xv = (t >= off) ? sd[t-off] : 0;
    __syncthreads();
    sd[t] += xv;
    __syncthreads();
  }
  int run = part[blockIdx.x] + sd[t] - s;
  if (base   < n) row_ptr[base]   = run; run += v0;
  if (base+1 < n) row_ptr[base+1] = run; run += v1;
  if (base+2 < n) row_ptr[base+2] = run; run += v2;
  if (base+3 < n) row_ptr[base+3] = run;
}

__global__ void fill_csr(const int* __restrict__ ei, const int* __restrict__ row_ptr,
                         int* __restrict__ cur, int* __restrict__ csr, int E, int nn){
  int e = blockIdx.x*256 + threadIdx.x;
  if (e < E){
    int d = ei[E+e];
    if ((unsigned)d < (unsigned)nn){
      int pos = row_ptr[d] + atomicAdd(&cur[d], 1);
      if ((unsigned)pos < (unsigned)E) csr[pos] = ei[e];
    }
  }
}

// ---- layer-1 aggregate + xres + LayerNorm + ELU; 1 wave/node
// weight dedup: lanes compute w[edge=lane>>3][head=lane&7] once, bpermute to consumers
__global__ __launch_bounds__(256) void agg1(
    const __hip_bfloat16* __restrict__ h1b,
    const float* __restrict__ as1, const float* __restrict__ ad1,
    const int* __restrict__ rowp, const int* __restrict__ csr,
    const __hip_bfloat16* __restrict__ xrB, const __hip_bfloat16* __restrict__ xrF,
    const float* __restrict__ bias1f, const float* __restrict__ gf,
    const float* __restrict__ bfta,
    const int* __restrict__ flag, void* __restrict__ dout, int nn, int Etot){
  int f32 = *flag;
  int w = threadIdx.x >> 6, lane = threadIdx.x & 63;
  int n = blockIdx.x*4 + w;
  if (n >= nn) return;
  int h = lane >> 3, c0 = lane*2;      // consumer role: head h, channels c0,c0+1
  int wh = lane & 7;                   // weight role: head wh, edge lane>>3
  const __hip_bfloat16* xr = f32 ? xrF : xrB;
  ushort2 xru = ((const ushort2*)(xr))[(size_t)n*64 + lane];
  float adc = ad1[n*8 + h];            // dst coeff for consumer head
  float adw = ad1[n*8 + wh];           // dst coeff for weight head
  float asn = as1[n*8 + h];
  unsigned hv0 = *(const unsigned*)(h1b + (size_t)n*128 + c0);
  int p0 = rowp[n], pe = rowp[n+1];
  if (p0 < 0) p0 = 0; if (pe > Etot) pe = Etot;
  int p0u = __builtin_amdgcn_readfirstlane(p0);
  int peu = __builtin_amdgcn_readfirstlane(pe);
  // self-loop
  float selfw = __expf(fminf(lrelu(asn + adc), 30.f));
  float acc0 = selfw*bflo(hv0);
  float acc1 = selfw*bfhi(hv0);
  float denp = 0.f;                    // per-lane partial denom (head wh)
  for (int b = p0u; b < peu; b += 16){
    // weight lanes: edges b+(lane>>3) and b+8+(lane>>3), head wh
    int e0i = b + (lane>>3);
    int e1i = e0i + 8;
    int j0 = e0i < peu ? e0i : peu-1;
    int j1 = e1i < peu ? e1i : peu-1;
    int s0 = csr[j0]; if ((unsigned)s0 >= (unsigned)nn) s0 = 0;
    int s1 = csr[j1]; if ((unsigned)s1 >= (unsigned)nn) s1 = 0;
    float av0 = as1[(size_t)s0*8 + wh];
    float av1 = as1[(size_t)s1*8 + wh];
    float w0 = __expf(fminf(lrelu(av0 + adw), 30.f)) * (e0i < peu ? 1.f : 0.f);
    float w1 = __expf(fminf(lrelu(av1 + adw), 30.f)) * (e1i < peu ? 1.f : 0.f);
    denp += w0 + w1;
    // gather h rows for up to 16 edges (scalar-indexed -> saddr loads, all in flight)
    unsigned hv[16];
    #pragma unroll
    for (int u=0;u<16;++u){
      int eu = b + u;
      int ju = eu < peu ? eu : peu-1;   // uniform -> s_load
      int su = csr[ju];
      if ((unsigned)su >= (unsigned)nn) su = 0;
      hv[u] = *(const unsigned*)(h1b + (size_t)su*128 + c0);
    }
    #pragma unroll
    for (int u=0;u<8;++u){
      float wb = __shfl(w0, u*8 + h);   // ds_bpermute, off the VALU
      acc0 += wb * bflo(hv[u]);
      acc1 += wb * bfhi(hv[u]);
    }
    #pragma unroll
    for (int u=0;u<8;++u){
      float wb = __shfl(w1, u*8 + h);
      acc0 += wb * bflo(hv[8+u]);
      acc1 += wb * bfhi(hv[8+u]);
    }
  }
  // reduce denom over lanes with same wh (bits 3..5), then fetch my head's total
  denp += __shfl_xor(denp, 8);
  denp += __shfl_xor(denp, 16);
  denp += __shfl_xor(denp, 32);
  float den = __shfl(denp, h) + selfw;   // lane h has wh==h
  float inv = 1.f/(den + 1e-16f);
  float o0 = acc0*inv + bfu(xru.x) + bias1f[c0];
  float o1 = acc1*inv + bfu(xru.y) + bias1f[c0+1];
  float s1 = o0 + o1, s2 = o0*o0 + o1*o1;
  #pragma unroll
  for (int off=32; off>0; off>>=1){
    s1 += __shfl_xor(s1, off);
    s2 += __shfl_xor(s2, off);
  }
  float mu  = s1 * (1.f/128.f);
  float var = s2 * (1.f/128.f) - mu*mu;
  float rstd = rsqrtf(var + 1e-5f);
  o0 = (o0 - mu)*rstd*gf[c0]   + bfta[c0];
  o1 = (o1 - mu)*rstd*gf[c0+1] + bfta[c0+1];
  o0 = o0 > 0.f ? o0 : __expf(o0) - 1.f;
  o1 = o1 > 0.f ? o1 : __expf(o1) - 1.f;
  if (!f32){
    __hip_bfloat162 o2; o2.x = __float2bfloat16(o0); o2.y = __float2bfloat16(o1);
    *(__hip_bfloat162*)((__hip_bfloat16*)dout + (size_t)n*128 + c0) = o2;
  } else {
    float2 o2; o2.x = o0; o2.y = o1;
    *(float2*)((float*)dout + (size_t)n*128 + c0) = o2;
  }
}

// ---- layer-2 aggregate; 1 wave/node, 1 ch/lane; weight dedup: lane e computes w[e]
__global__ __launch_bounds__(256) void agg2(const __hip_bfloat16* __restrict__ h2b,
    const float* __restrict__ as2, const float* __restrict__ ad2,
    const int* __restrict__ rowp, const int* __restrict__ csr,
    const float* __restrict__ bias2f,
    const int* __restrict__ flag, void* __restrict__ dout, int nn, int Etot){
  int f32 = *flag;
  int w = threadIdx.x >> 6, lane = threadIdx.x & 63;
  int n = blockIdx.x*4 + w;
  if (n >= nn) return;
  float adst = ad2[n];
  float selfw = __expf(fminf(lrelu(as2[n] + adst), 30.f));
  float acc = selfw * bfu(((const unsigned short*)h2b)[(size_t)n*64 + lane]);
  float denp = 0.f;
  int p0 = rowp[n], pe = rowp[n+1];
  if (p0 < 0) p0 = 0; if (pe > Etot) pe = Etot;
  int p0u = __builtin_amdgcn_readfirstlane(p0);
  int peu = __builtin_amdgcn_readfirstlane(pe);
  for (int b = p0u; b < peu; b += 64){
    // weight lanes: edge b+lane
    int ei = b + lane;
    int ji = ei < peu ? ei : peu-1;
    int si = csr[ji]; if ((unsigned)si >= (unsigned)nn) si = 0;
    float av = as2[si];
    float wv = __expf(fminf(lrelu(av + adst), 30.f)) * (ei < peu ? 1.f : 0.f);
    denp += wv;
    int lim = peu - b; if (lim > 64) lim = 64;
    for (int jb = 0; jb < lim; jb += 16){
      unsigned short hv[16];
      #pragma unroll
      for (int u=0;u<16;++u){
        int eu = b + jb + u;
        int ju = eu < peu ? eu : peu-1;   // uniform -> s_load
        int su = csr[ju];
        if ((unsigned)su >= (unsigned)nn) su = 0;
        hv[u] = ((const unsigned short*)h2b)[(size_t)su*64 + lane];
      }
      #pragma unroll
      for (int u=0;u<16;++u){
        float wb = __shfl(wv, jb + u);    // broadcast edge weight
        acc += wb * bfu(hv[u]);
      }
    }
  }
  denp += __shfl_xor(denp, 1);
  denp += __shfl_xor(denp, 2);
  denp += __shfl_xor(denp, 4);
  denp += __shfl_xor(denp, 8);
  denp += __shfl_xor(denp, 16);
  denp += __shfl_xor(denp, 32);
  float den = denp + selfw;
  float o = acc/(den + 1e-16f) + bias2f[lane];
  size_t ofs = (size_t)nn*128 + (size_t)n*64 + lane;
  if (!f32) ((__hip_bfloat16*)dout)[ofs] = __float2bfloat16(o);
  else      ((float*)dout)[ofs] = o;
}

extern "C" void kernel_launch(void* const* d_in, const int* in_sizes, int n_in,
                              void* d_out, int out_size, void* d_ws, size_t ws_size,
                              hipStream_t stream){
  (void)n_in; (void)out_size; (void)ws_size;
  const void* x     = d_in[0];
  const int*  ei    = (const int*)d_in[1];
  const void* W1    = d_in[2];
  const void* a1s   = d_in[3];
  const void* a1d   = d_in[4];
  const void* b1    = d_in[5];
  const void* resW  = d_in[6];
  const void* g     = d_in[7];
  const void* bt    = d_in[8];
  const void* W2    = d_in[9];
  const void* a2s   = d_in[10];
  const void* a2d   = d_in[11];
  const void* b2    = d_in[12];

  int N = in_sizes[0] / 128;
  int E = in_sizes[1] / 2;

  __hip_bfloat16* xrB = (__hip_bfloat16*)d_out;
  __hip_bfloat16* xrF = (__hip_bfloat16*)((float*)d_out + (size_t)N*128);

  char* ws = (char*)d_ws;
  size_t o = 0;
  auto alloc = [&](size_t bytes)->char*{ char* r = ws + o; o = (o + bytes + 255) & ~(size_t)255; return r; };
  int*   flag = (int*)  alloc(4);
  int*   part = (int*)  alloc(4096);
  int*   rowp = (int*)  alloc(((size_t)N+1)*4);
  int*   cnt  = (int*)  alloc((size_t)N*4);
  float* as1  = (float*)alloc((size_t)N*8*4);
  float* ad1  = (float*)alloc((size_t)N*8*4);
  int*   csr  = (int*)  alloc((size_t)E*4);
  __hip_bfloat16* h1b = (__hip_bfloat16*)alloc((size_t)N*128*2);
  __hip_bfloat16* Bt1 = (__hip_bfloat16*)alloc(65536);
  __hip_bfloat16* W2t = (__hip_bfloat16*)alloc(16384);
  float* att1s  = (float*)alloc(512);
  float* att1d  = (float*)alloc(512);
  float* bias1f = (float*)alloc(512);
  float* gfv    = (float*)alloc(512);
  float* bfv    = (float*)alloc(512);
  float* att2s  = (float*)alloc(256);
  float* att2d  = (float*)alloc(256);
  float* bias2f = (float*)alloc(256);
  __hip_bfloat16* h2b = h1b;
  float* as2 = as1;
  float* ad2 = ad1;

  int EB = (E + 255)/256;
  int NB = (N + 1023)/1024;

  (void)hipMemsetAsync(flag, 0, 4, stream);
  (void)hipMemsetAsync(cnt,  0, (size_t)N*4, stream);
  detect<<<16, 256, 0, stream>>>((const unsigned short*)x, flag);
  prep<<<164, 256, 0, stream>>>(W1, resW, W2, a1s, a1d, b1, g, bt, a2s, a2d, b2,
                                Bt1, W2t, att1s, att1d, bias1f, gfv, bfv,
                                att2s, att2d, bias2f, flag);
  gemm1<<<(N+15)/16, 256, 0, stream>>>(x, Bt1, h1b, xrB, xrF, flag, N);
  count_edges<<<EB, 256, 0, stream>>>(ei, cnt, E, N);
  scan_part<<<NB, 256, 0, stream>>>(cnt, part, N);
  scan_mid<<<1, 256, 0, stream>>>(part, NB, rowp, N);
  scan_write<<<NB, 256, 0, stream>>>(cnt, part, rowp, N);
  (void)hipMemsetAsync(cnt, 0, (size_t)N*4, stream);
  fill_csr<<<EB, 256, 0, stream>>>(ei, rowp, cnt, csr, E, N);
  attdot1<<<(N*8 + 255)/256, 256, 0, stream>>>(h1b, att1s, att1d, as1, ad1, N);
  agg1<<<(N+3)/4, 256, 0, stream>>>(h1b, as1, ad1, rowp, csr, xrB, xrF,
                                    bias1f, gfv, bfv, flag, d_out, N, E);
  gemm2<<<(N+15)/16, 256, 0, stream>>>(d_out, W2t, h2b, flag, N);
  attdot2<<<(N+255)/256, 256, 0, stream>>>(h2b, att2s, att2d, as2, ad2, N);
  agg2<<<(N+3)/4, 256, 0, stream>>>(h2b, as2, ad2, rowp, csr, bias2f, flag, d_out, N, E);
}